// Round 1
// baseline (873.309 us; speedup 1.0000x reference)
//
#include <hip/hip_runtime.h>

// Problem constants (from reference)
#define NROWS   262144
#define IN_C    64
#define OUT_C   64
#define SLOTS   9

#define BLOCK      1024                   // 16 waves; 2 blocks/CU (LDS) -> 32 waves/CU = 100% occ
#define ROWS_PER_WAVE 16
#define TILE_ROWS  (16 * ROWS_PER_WAVE)   // 256 rows per block-tile
#define NTILES     (NROWS / TILE_ROWS)    // 1024
#define GRID       512                    // 2 blocks/CU, 2 tiles/block

typedef short short8 __attribute__((ext_vector_type(8)));
typedef float f32x4  __attribute__((ext_vector_type(4)));

struct XPtrs { const float* p[SLOTS]; };

// fp32 -> bf16 round-to-nearest-even (bit trick; NaN not a concern here)
__device__ __forceinline__ short bfr(float f) {
  unsigned u = __builtin_bit_cast(unsigned, f);
  u = u + 0x7FFFu + ((u >> 16) & 1u);
  return (short)(u >> 16);
}

__device__ __forceinline__ short8 pack8(float4 a, float4 b) {
  short8 r;
  r[0] = bfr(a.x); r[1] = bfr(a.y); r[2] = bfr(a.z); r[3] = bfr(a.w);
  r[4] = bfr(b.x); r[5] = bfr(b.y); r[6] = bfr(b.z); r[7] = bfr(b.w);
  return r;
}

// Issue all 4 A-loads for one slot (16 rows x 64 cols, this wave's stripe).
__device__ __forceinline__ void load_slot(const float* __restrict__ x,
                                          int row0, int n16, int quad,
                                          float4 v[4]) {
  const float* xr = x + (size_t)(row0 + n16) * IN_C + (quad << 3);
  v[0] = *(const float4*)(xr + 0);
  v[1] = *(const float4*)(xr + 4);
  v[2] = *(const float4*)(xr + 32);
  v[3] = *(const float4*)(xr + 36);
}

// out[n,o] = sum_k sum_c x_k[n,c] * W[k,o,c] + sum_k bias[k,o]
// MFMA mfma_f32_16x16x32_bf16:
//   A[m = lane&15][k = (lane>>4)*8 + j]            (m = row)
//   B[k = (lane>>4)*8 + j][n = lane&15]            (n indexes an output-col GROUP)
//   C/D: col = lane&15, row = (lane>>4)*4 + reg
//
// Column permutation: MFMA instance `ot` computes output col o = 4*n16 + ot
// (staged into B accordingly). So lane (quad,n16) holds, per row r, the four
// ADJACENT cols {4*n16 .. 4*n16+3} across acc[0..3][r]  ->  full-float4,
// full-cache-line coalesced stores (1 KB per wave-instr), nt-safe.
__global__ __launch_bounds__(BLOCK, 8)   // 8 waves/EU: pins VGPR <= 64 for 2 blocks/CU
void scatter_vertical_kernel(XPtrs xs, const float* __restrict__ W,
                             const float* __restrict__ bias,
                             float* __restrict__ out) {
  // B fragments in exact MFMA order: [slot][h][ot][lane] -> short8
  // 9*2*4*64 * 16B = 73728 B; 2 blocks/CU on 160 KiB LDS.
  __shared__ short8 sB[SLOTS * 2 * 4 * 64];
  __shared__ float  sBias[OUT_C];

  const int tid = threadIdx.x;

  // ---- stage weights fp32->bf16 into B-fragment order (once per block) ----
  {
    const float4* W4 = (const float4*)W;
    unsigned short* sBu = (unsigned short*)sB;
    for (int i4 = tid; i4 < SLOTS * 64 * 16; i4 += BLOCK) {
      float4 w = W4[i4];
      int c    = (i4 & 15) << 2;        // 0..60, step 4
      int o    = (i4 >> 4) & 63;
      int slot = i4 >> 10;
      int h  = c >> 5;                  // which 32-col half (K-step parity)
      int q  = (c >> 3) & 3;            // quad owning these cols
      int j0 = c & 7;                   // 0 or 4 within the 8-elem fragment
      int ot = o & 3;                   // MFMA instance <- low 2 bits of o
      int l  = (q << 4) | (o >> 2);     // lane = quad*16 + n, n = o>>2
      int base = ((((slot * 2 + h) * 4 + ot) * 64 + l) << 3) + j0;
      sBu[base + 0] = (unsigned short)bfr(w.x);
      sBu[base + 1] = (unsigned short)bfr(w.y);
      sBu[base + 2] = (unsigned short)bfr(w.z);
      sBu[base + 3] = (unsigned short)bfr(w.w);
    }
    if (tid < OUT_C) {
      float s = 0.f;
      for (int k = 0; k < SLOTS; ++k) s += bias[k * OUT_C + tid];
      sBias[tid] = s;
    }
  }
  __syncthreads();

  const int wave = tid >> 6;
  const int lane = tid & 63;
  const int n16  = lane & 15;
  const int quad = lane >> 4;

  for (int tile = blockIdx.x; tile < NTILES; tile += gridDim.x) {
    const int row0 = tile * TILE_ROWS + wave * ROWS_PER_WAVE;

    f32x4 acc[4];
#pragma unroll
    for (int ot = 0; ot < 4; ++ot) acc[ot] = (f32x4){0.f, 0.f, 0.f, 0.f};

    // ---- depth-2 software-pipelined K loop (9 slots, full unroll) ----
    float4 buf[3][4];                      // 3-deep register ring, 48 VGPR
    load_slot(xs.p[0], row0, n16, quad, buf[0]);
    load_slot(xs.p[1], row0, n16, quad, buf[1]);

#pragma unroll
    for (int k = 0; k < SLOTS; ++k) {
      if (k + 2 < SLOTS)
        load_slot(xs.p[k + 2], row0, n16, quad, buf[(k + 2) % 3]);

      float4* c = buf[k % 3];
      short8 a0 = pack8(c[0], c[1]);       // K-step h=0 (cols 0..31)
      short8 a1 = pack8(c[2], c[3]);       // K-step h=1 (cols 32..63)

#pragma unroll
      for (int ot = 0; ot < 4; ++ot) {
        short8 b0 = sB[k * 512 + ot * 64 + lane];        // h=0
        short8 b1 = sB[k * 512 + 256 + ot * 64 + lane];  // h=1
        acc[ot] = __builtin_amdgcn_mfma_f32_16x16x32_bf16(a0, b0, acc[ot], 0, 0, 0);
        acc[ot] = __builtin_amdgcn_mfma_f32_16x16x32_bf16(a1, b1, acc[ot], 0, 0, 0);
      }
    }

    // ---- epilogue: bias add + full-line coalesced float4 stores ----
    // Lane (quad,n16) owns rows row0+quad*4+r, cols 4*n16..4*n16+3 (acc[0..3][r]).
    // Each store instr: 16 lanes x 16 B contiguous per row, 4 rows -> 8 full
    // 128 B lines, so nontemporal is safe (no partial-line evict / RFO).
    const f32x4 b4 = ((const f32x4*)sBias)[n16];
#pragma unroll
    for (int r = 0; r < 4; ++r) {
      const size_t row = row0 + quad * 4 + r;
      f32x4 v;
      v[0] = acc[0][r] + b4[0];
      v[1] = acc[1][r] + b4[1];
      v[2] = acc[2][r] + b4[2];
      v[3] = acc[3][r] + b4[3];
      __builtin_nontemporal_store(v, (f32x4*)(out + row * OUT_C + (n16 << 2)));
    }
  }
}

extern "C" void kernel_launch(void* const* d_in, const int* in_sizes, int n_in,
                              void* d_out, int out_size, void* d_ws, size_t ws_size,
                              hipStream_t stream) {
  XPtrs xs;
  for (int i = 0; i < SLOTS; ++i) xs.p[i] = (const float*)d_in[i];
  const float* W    = (const float*)d_in[SLOTS];       // [9, 64, 64]
  const float* bias = (const float*)d_in[SLOTS + 1];   // [9, 64]
  float* out = (float*)d_out;                          // [N, 64] fp32

  hipLaunchKernelGGL(scatter_vertical_kernel, dim3(GRID), dim3(BLOCK), 0, stream,
                     xs, W, bias, out);
}

// Round 2
// 770.865 us; speedup vs baseline: 1.1329x; 1.1329x over previous
//
#include <hip/hip_runtime.h>

// Problem constants (from reference)
#define NROWS   262144
#define IN_C    64
#define OUT_C   64
#define SLOTS   9

#define BLOCK      1024                   // 16 waves; 2 blocks/CU (LDS) -> 32 waves/CU = 100% occ
#define ROWS_PER_WAVE 16
#define TILE_ROWS  (16 * ROWS_PER_WAVE)   // 256 rows per block-tile
#define NTILES     (NROWS / TILE_ROWS)    // 1024
#define GRID       512                    // 2 blocks/CU, 2 tiles/block

typedef short short8 __attribute__((ext_vector_type(8)));
typedef float f32x4  __attribute__((ext_vector_type(4)));

struct XPtrs { const float* p[SLOTS]; };

// fp32 -> bf16 round-to-nearest-even (bit trick; NaN not a concern here)
__device__ __forceinline__ short bfr(float f) {
  unsigned u = __builtin_bit_cast(unsigned, f);
  u = u + 0x7FFFu + ((u >> 16) & 1u);
  return (short)(u >> 16);
}

__device__ __forceinline__ short8 pack8(float4 a, float4 b) {
  short8 r;
  r[0] = bfr(a.x); r[1] = bfr(a.y); r[2] = bfr(a.z); r[3] = bfr(a.w);
  r[4] = bfr(b.x); r[5] = bfr(b.y); r[6] = bfr(b.z); r[7] = bfr(b.w);
  return r;
}

// Issue all 4 A-loads for one slot (16 rows x 64 cols, this wave's stripe).
__device__ __forceinline__ void load_slot(const float* __restrict__ x,
                                          int row0, int n16, int quad,
                                          float4 v[4]) {
  const float* xr = x + (size_t)(row0 + n16) * IN_C + (quad << 3);
  v[0] = *(const float4*)(xr + 0);
  v[1] = *(const float4*)(xr + 4);
  v[2] = *(const float4*)(xr + 32);
  v[3] = *(const float4*)(xr + 36);
}

// out[n,o] = sum_k sum_c x_k[n,c] * W[k,o,c] + sum_k bias[k,o]
// MFMA mfma_f32_16x16x32_bf16:
//   A[m = lane&15][k = (lane>>4)*8 + j]            (m = row)
//   B[k = (lane>>4)*8 + j][n = lane&15]            (n indexes an output-col GROUP)
//   C/D: col = lane&15, row = (lane>>4)*4 + reg
//
// Column permutation: MFMA instance `ot` computes output col o = 4*n16 + ot
// (staged into B accordingly). So lane (quad,n16) holds, per row r, the four
// ADJACENT cols {4*n16 .. 4*n16+3} across acc[0..3][r]  ->  full-float4,
// full-cache-line coalesced stores (1 KB per wave-instr), nt-safe.
//
// __launch_bounds__ 2nd arg: EMPIRICALLY hipcc treats it as CUDA-style
// min-BLOCKS-per-CU on this toolchain: (512,4)->64 VGPR, (1024,8)->32 VGPR
// (the latter spilled ~600 MB of scratch, round-1 regression). (1024,2)
// => 2 blocks x 16 waves = 32 waves/CU => 64-VGPR budget, which this body
// fits naturally (round-0 evidence). Safe under the waves/EU reading too
// (budget 256, natural usage 64).
__global__ __launch_bounds__(BLOCK, 2)
void scatter_vertical_kernel(XPtrs xs, const float* __restrict__ W,
                             const float* __restrict__ bias,
                             float* __restrict__ out) {
  // B fragments in exact MFMA order: [slot][h][ot][lane] -> short8
  // 9*2*4*64 * 16B = 73728 B; 2 blocks/CU on 160 KiB LDS.
  __shared__ short8 sB[SLOTS * 2 * 4 * 64];
  __shared__ float  sBias[OUT_C];

  const int tid = threadIdx.x;

  // ---- stage weights fp32->bf16 into B-fragment order (once per block) ----
  {
    const float4* W4 = (const float4*)W;
    unsigned short* sBu = (unsigned short*)sB;
    for (int i4 = tid; i4 < SLOTS * 64 * 16; i4 += BLOCK) {
      float4 w = W4[i4];
      int c    = (i4 & 15) << 2;        // 0..60, step 4
      int o    = (i4 >> 4) & 63;
      int slot = i4 >> 10;
      int h  = c >> 5;                  // which 32-col half (K-step parity)
      int q  = (c >> 3) & 3;            // quad owning these cols
      int j0 = c & 7;                   // 0 or 4 within the 8-elem fragment
      int ot = o & 3;                   // MFMA instance <- low 2 bits of o
      int l  = (q << 4) | (o >> 2);     // lane = quad*16 + n, n = o>>2
      int base = ((((slot * 2 + h) * 4 + ot) * 64 + l) << 3) + j0;
      sBu[base + 0] = (unsigned short)bfr(w.x);
      sBu[base + 1] = (unsigned short)bfr(w.y);
      sBu[base + 2] = (unsigned short)bfr(w.z);
      sBu[base + 3] = (unsigned short)bfr(w.w);
    }
    if (tid < OUT_C) {
      float s = 0.f;
      for (int k = 0; k < SLOTS; ++k) s += bias[k * OUT_C + tid];
      sBias[tid] = s;
    }
  }
  __syncthreads();

  const int wave = tid >> 6;
  const int lane = tid & 63;
  const int n16  = lane & 15;
  const int quad = lane >> 4;

  for (int tile = blockIdx.x; tile < NTILES; tile += gridDim.x) {
    const int row0 = tile * TILE_ROWS + wave * ROWS_PER_WAVE;

    f32x4 acc[4];
#pragma unroll
    for (int ot = 0; ot < 4; ++ot) acc[ot] = (f32x4){0.f, 0.f, 0.f, 0.f};

    // ---- depth-2 software-pipelined K loop (9 slots, full unroll) ----
    float4 buf[3][4];                      // 3-deep register ring, 48 VGPR
    load_slot(xs.p[0], row0, n16, quad, buf[0]);
    load_slot(xs.p[1], row0, n16, quad, buf[1]);

#pragma unroll
    for (int k = 0; k < SLOTS; ++k) {
      if (k + 2 < SLOTS)
        load_slot(xs.p[k + 2], row0, n16, quad, buf[(k + 2) % 3]);

      float4* c = buf[k % 3];
      short8 a0 = pack8(c[0], c[1]);       // K-step h=0 (cols 0..31)
      short8 a1 = pack8(c[2], c[3]);       // K-step h=1 (cols 32..63)

#pragma unroll
      for (int ot = 0; ot < 4; ++ot) {
        short8 b0 = sB[k * 512 + ot * 64 + lane];        // h=0
        short8 b1 = sB[k * 512 + 256 + ot * 64 + lane];  // h=1
        acc[ot] = __builtin_amdgcn_mfma_f32_16x16x32_bf16(a0, b0, acc[ot], 0, 0, 0);
        acc[ot] = __builtin_amdgcn_mfma_f32_16x16x32_bf16(a1, b1, acc[ot], 0, 0, 0);
      }
    }

    // ---- epilogue: bias add + full-line coalesced float4 stores ----
    // Lane (quad,n16) owns rows row0+quad*4+r, cols 4*n16..4*n16+3 (acc[0..3][r]).
    // Each store instr: 16 lanes x 16 B contiguous per row, 4 rows -> 8 full
    // 128 B lines, so nontemporal is safe (no partial-line evict / RFO).
    const f32x4 b4 = ((const f32x4*)sBias)[n16];
#pragma unroll
    for (int r = 0; r < 4; ++r) {
      const size_t row = row0 + quad * 4 + r;
      f32x4 v;
      v[0] = acc[0][r] + b4[0];
      v[1] = acc[1][r] + b4[1];
      v[2] = acc[2][r] + b4[2];
      v[3] = acc[3][r] + b4[3];
      __builtin_nontemporal_store(v, (f32x4*)(out + row * OUT_C + (n16 << 2)));
    }
  }
}

extern "C" void kernel_launch(void* const* d_in, const int* in_sizes, int n_in,
                              void* d_out, int out_size, void* d_ws, size_t ws_size,
                              hipStream_t stream) {
  XPtrs xs;
  for (int i = 0; i < SLOTS; ++i) xs.p[i] = (const float*)d_in[i];
  const float* W    = (const float*)d_in[SLOTS];       // [9, 64, 64]
  const float* bias = (const float*)d_in[SLOTS + 1];   // [9, 64]
  float* out = (float*)d_out;                          // [N, 64] fp32

  hipLaunchKernelGGL(scatter_vertical_kernel, dim3(GRID), dim3(BLOCK), 0, stream,
                     xs, W, bias, out);
}

// Round 3
// 545.752 us; speedup vs baseline: 1.6002x; 1.4125x over previous
//
#include <hip/hip_runtime.h>

// Problem constants (from reference)
#define NROWS   262144
#define IN_C    64
#define OUT_C   64
#define SLOTS   9

#define BLOCK      512                    // 8 waves
#define TILE_ROWS  128                    // 16 rows per wave
#define NTILES     (NROWS / TILE_ROWS)    // 2048
#define GRID       256                    // 1 persistent block/CU (139.5 KiB LDS)
#define TPB        (NTILES / GRID)        // 8 tiles per block

typedef short short8 __attribute__((ext_vector_type(8)));
typedef float f32x4  __attribute__((ext_vector_type(4)));

struct XPtrs { const float* p[SLOTS]; };

// fp32 -> bf16 round-to-nearest-even (bit trick; NaN not a concern here)
__device__ __forceinline__ short bfr(float f) {
  unsigned u = __builtin_bit_cast(unsigned, f);
  u = u + 0x7FFFu + ((u >> 16) & 1u);
  return (short)(u >> 16);
}

__device__ __forceinline__ short8 pack8(float4 a, float4 b) {
  short8 r;
  r[0] = bfr(a.x); r[1] = bfr(a.y); r[2] = bfr(a.z); r[3] = bfr(a.w);
  r[4] = bfr(b.x); r[5] = bfr(b.y); r[6] = bfr(b.z); r[7] = bfr(b.w);
  return r;
}

// Async 16B global->LDS (DMA; no VGPR round-trip, tracked by vmcnt).
#define GLL16(gp, lp) __builtin_amdgcn_global_load_lds(                        \
    (const __attribute__((address_space(1))) void*)(gp),                       \
    (__attribute__((address_space(3))) void*)(lp), 16, 0, 0)

// ---- A-tile staging --------------------------------------------------------
// LDS layout (per buffer): chunk-major sA[c][row], c = 16B chunk (4 floats)
// of the input row: chunk (c,row) holds x[row0+row][4c..4c+3].
// gload_lds writes linearly (wave-uniform base + lane*16), so the CHUNK-MAJOR
// order is produced by permuting the per-lane GLOBAL source address (m173):
//   linear idx L = i*512 + wave*64 + lane  ->  c = L>>7, row = L&127
//   => c = i*4 + (wave>>1), row = (wave&1)*64 + lane.
// Read side: 16 consecutive lanes (n16) read 256 B contiguous -> conflict-free.
__device__ __forceinline__ void stage_slot(const float* __restrict__ x, int row0,
                                           float4* sAbuf, int wave, int lane) {
  const int row = ((wave & 1) << 6) + lane;
  const float* g = x + (size_t)(row0 + row) * IN_C + ((wave >> 1) << 2);
#pragma unroll
  for (int i = 0; i < 4; ++i) {
    // chunk c = i*4 + (wave>>1)  ->  col(floats) = c*4 = i*16 + (wave>>1)*4
    GLL16(g + i * 16, sAbuf + i * 512 + wave * 64);
  }
}

// ---- per-slot MFMA from LDS ------------------------------------------------
// A fragment (16x16x32): lane(quad,n16) holds row n16 (of this wave's 16),
// cols quad*8..+7 (h=0) and 32+quad*8..+7 (h=1) == chunks {2q,2q+1} / {8+2q,9+2q}.
__device__ __forceinline__ void compute_slot(const float4* sAp, const short8* sBk,
                                             int wave, int quad, int n16, int lane,
                                             f32x4 acc[4]) {
  const int r = wave * 16 + n16;
  float4 a00 = sAp[(2 * quad + 0) * 128 + r];
  float4 a01 = sAp[(2 * quad + 1) * 128 + r];
  float4 a10 = sAp[(8 + 2 * quad) * 128 + r];
  float4 a11 = sAp[(9 + 2 * quad) * 128 + r];
  short8 a0 = pack8(a00, a01);          // K-step h=0 (cols 0..31)
  short8 a1 = pack8(a10, a11);          // K-step h=1 (cols 32..63)
#pragma unroll
  for (int ot = 0; ot < 4; ++ot) {
    short8 b0 = sBk[ot * 64 + lane];          // h=0
    short8 b1 = sBk[256 + ot * 64 + lane];    // h=1
    acc[ot] = __builtin_amdgcn_mfma_f32_16x16x32_bf16(a0, b0, acc[ot], 0, 0, 0);
    acc[ot] = __builtin_amdgcn_mfma_f32_16x16x32_bf16(a1, b1, acc[ot], 0, 0, 0);
  }
}

// out[n,o] = sum_k sum_c x_k[n,c] * W[k,o,c] + sum_k bias[k,o]
//
// Round-3 structure: the kernel is MLP-limited (16 waves/CU register-capped,
// ~2 KB/CU of loads in flight -> ~1.7 TB/s fetch). Fix: VGPR-free async
// staging via global_load_lds, double-buffered 32 KB A-tiles, counted
// s_waitcnt vmcnt(4) + raw s_barrier (prefetch stays in flight across the
// barrier; never drain in steady state). 32 KB in flight/CU * 256 CU = 8 MB
// outstanding >= the ~4 MB latency-BW product -> HBM-saturating.
// Stores: PLAIN write-back (nontemporal was the 8x write amplification).
__global__ __launch_bounds__(BLOCK, 2)
void scatter_vertical_kernel(XPtrs xs, const float* __restrict__ W,
                             const float* __restrict__ bias,
                             float* __restrict__ out) {
  __shared__ short8 sB[SLOTS * 2 * 4 * 64];   // 73728 B, B fragments (bf16)
  __shared__ float4 sA[2 * 16 * 128];         // 65536 B, A double-buffer (fp32)
  __shared__ float  sBias[OUT_C];             // 256 B
  // total 139.5 KiB -> 1 block/CU

  const int tid  = threadIdx.x;
  const int wave = tid >> 6;
  const int lane = tid & 63;
  const int n16  = lane & 15;
  const int quad = lane >> 4;

  // ---- prologue: kick off first A-tile DMA, then stage weights -------------
  const int tile0_row0 = blockIdx.x * TILE_ROWS;
  stage_slot(xs.p[0], tile0_row0, (float4*)sA, wave, lane);

  {
    const float4* W4 = (const float4*)W;
    unsigned short* sBu = (unsigned short*)sB;
    for (int i4 = tid; i4 < SLOTS * 64 * 16; i4 += BLOCK) {
      float4 w = W4[i4];
      int c    = (i4 & 15) << 2;        // 0..60, step 4
      int o    = (i4 >> 4) & 63;
      int slot = i4 >> 10;
      int h  = c >> 5;                  // which 32-col half (K-step parity)
      int q  = (c >> 3) & 3;            // quad owning these cols
      int j0 = c & 7;                   // 0 or 4 within the 8-elem fragment
      int ot = o & 3;                   // MFMA instance <- low 2 bits of o
      int l  = (q << 4) | (o >> 2);     // lane = quad*16 + n, n = o>>2
      int base = ((((slot * 2 + h) * 4 + ot) * 64 + l) << 3) + j0;
      sBu[base + 0] = (unsigned short)bfr(w.x);
      sBu[base + 1] = (unsigned short)bfr(w.y);
      sBu[base + 2] = (unsigned short)bfr(w.z);
      sBu[base + 3] = (unsigned short)bfr(w.w);
    }
    if (tid < OUT_C) {
      float s = 0.f;
      for (int k = 0; k < SLOTS; ++k) s += bias[k * OUT_C + tid];
      sBias[tid] = s;
    }
  }
  __syncthreads();   // drains vmcnt(0) too: tile0/slot0 DMA complete after this

  // ---- main loop: 8 tiles x 9 slots, flat double-buffered pipeline ---------
  for (int j = 0; j < TPB; ++j) {
    const int row0  = (blockIdx.x + j * GRID) * TILE_ROWS;
    const int row0n = (blockIdx.x + (j + 1) * GRID) * TILE_ROWS;

    f32x4 acc[4];
#pragma unroll
    for (int ot = 0; ot < 4; ++ot) acc[ot] = (f32x4){0.f, 0.f, 0.f, 0.f};

#pragma unroll
    for (int k = 0; k < SLOTS; ++k) {
      // buffer parity for iteration (j,k): p = (j*9+k)&1 = (j+k)&1
      const int p = (j + k) & 1;
      float4* bufN = (float4*)sA + (p ^ 1) * 2048;

      // issue next stage (slot k+1 of this tile, or slot 0 of next tile)
      if (k + 1 < SLOTS) {
        stage_slot(xs.p[k + 1], row0, bufN, wave, lane);
        asm volatile("s_waitcnt vmcnt(4)" ::: "memory");   // wait slot k only
      } else if (j + 1 < TPB) {
        stage_slot(xs.p[0], row0n, bufN, wave, lane);
        asm volatile("s_waitcnt vmcnt(4)" ::: "memory");
      } else {
        asm volatile("s_waitcnt vmcnt(0)" ::: "memory");   // last slot: drain
      }
      __builtin_amdgcn_s_barrier();    // all waves' slot-k chunks now in LDS

      compute_slot((const float4*)sA + p * 2048, sB + k * 512,
                   wave, quad, n16, lane, acc);

      // close the read-vs-overwrite race: LDS->reg transfers done, then barrier
      asm volatile("s_waitcnt lgkmcnt(0)" ::: "memory");
      __builtin_amdgcn_s_barrier();
    }

    // ---- epilogue: bias add + PLAIN coalesced float4 stores ----------------
    // Lane (quad,n16) holds rows wrow0+quad*4+r, cols 4*n16..4*n16+3.
    // 16 lanes x 16 B contiguous per row; full 128 B lines; write-back L2
    // merges and writes each line to HBM exactly once (no nt!).
    const f32x4 b4 = ((const f32x4*)sBias)[n16];
    const int wrow0 = row0 + wave * 16;
#pragma unroll
    for (int r = 0; r < 4; ++r) {
      const size_t row = wrow0 + quad * 4 + r;
      f32x4 v;
      v[0] = acc[0][r] + b4[0];
      v[1] = acc[1][r] + b4[1];
      v[2] = acc[2][r] + b4[2];
      v[3] = acc[3][r] + b4[3];
      *(f32x4*)(out + row * OUT_C + (n16 << 2)) = v;
    }
  }
}

extern "C" void kernel_launch(void* const* d_in, const int* in_sizes, int n_in,
                              void* d_out, int out_size, void* d_ws, size_t ws_size,
                              hipStream_t stream) {
  XPtrs xs;
  for (int i = 0; i < SLOTS; ++i) xs.p[i] = (const float*)d_in[i];
  const float* W    = (const float*)d_in[SLOTS];       // [9, 64, 64]
  const float* bias = (const float*)d_in[SLOTS + 1];   // [9, 64]
  float* out = (float*)d_out;                          // [N, 64] fp32

  hipLaunchKernelGGL(scatter_vertical_kernel, dim3(GRID), dim3(BLOCK), 0, stream,
                     xs, W, bias, out);
}